// Round 17
// baseline (205.042 us; speedup 1.0000x reference)
//
#include <hip/hip_runtime.h>

#define H 512
#define W 512
#define TH 128                // tile rows
#define TW 128                // tile cols
#define NT 512
#define SW 168                // LDS row stride in halfs (84 dwords; 8 staged-pad)
#define SROWS 154
#define NBANKS 16
#define BANK_STRIDE 16
// 128x128 tile, px (y,x) at LDS (13+y, 16+x) fp16, staged cols 0..159.
//
// MEASURED: R15 64x64+diet 135us; R16 64x128 125us (occ 57, VGPR 40,
// WRITE 128B, conflicts 2.1e7 hidden). Geometry amortization confirmed.
// THIS ROUND: 128x128. Per px: erode 15.19->13.97 (-8%), staging
// 1.74->1.48 (-15%), barriers halved again. LDS 50.5KB -> 3 blocks by
// LDS; VGPR +32 (2nd-row skel+t0) may cap 16 waves/CU. Dilate for 2
// consecutive rows shares middle rows (8 h8 reads vs 12) + shared maxes.
// ARBITRATION: WRITE_SIZE must stay ~256B (R14 spill lesson).
//
// In-place safety: pass R writes rows [13-R,140+R], reads [12-R,141+R]
// == prev pass's written rows (margin 0); all reads (incl. t0)
// pre-barrier-A, writes A->B, dilate after B. Stage rows 1..152 (R=11
// reads exactly [1,152]).
// COLUMN TRIM (identical to R16): pass R consumed cols [16-R,143+R].
// G=20/GLO=0 (R>=9, writes [0,159]), G=18/GLO=1 (R<=8, writes [8,151]).
// V(11)=[1,158] ... V(1)=[15,144] exact = final dilate cols; pad cols
// 160..167 uninit, feeds only never-consumed edge cols (proof as R16).
// items: min 1170 (R=1) >= 2*NT -> k=0,1 unconditional; max 1500 < 3*NT
// -> k=2 guarded.

typedef _Float16 h8 __attribute__((ext_vector_type(8)));
typedef _Float16 h4 __attribute__((ext_vector_type(4)));

__device__ __forceinline__ float sigmf(float x) {
  // 1/(1+e^-x) with hw rcp: full IEEE divide is ~9 VALU ops, rcp is 1.
  return __builtin_amdgcn_rcpf(1.0f + __expf(-x));
}
__device__ __forceinline__ float4 ld4(const float* p) { return *(const float4*)p; }

__device__ __forceinline__ h8 max3v(h8 a, h8 b, h8 c) {
  return __builtin_elementwise_max(__builtin_elementwise_max(a, b), c);
}
__device__ __forceinline__ h8 shl1(h8 v, _Float16 e) {
  h8 r = __builtin_shufflevector(v, v, 7, 0, 1, 2, 3, 4, 5, 6);
  r[0] = e;
  return r;
}
__device__ __forceinline__ h8 shr1(h8 v, _Float16 e) {
  h8 r = __builtin_shufflevector(v, v, 1, 2, 3, 4, 5, 6, 7, 0);
  r[7] = e;
  return r;
}
// b32 loads of half pairs (keeps ds_read2 mergeability), extract one half.
__device__ __forceinline__ _Float16 hi_half(const _Float16* p) {
  unsigned v = *(const unsigned*)p;
  return __builtin_bit_cast(_Float16, (unsigned short)(v >> 16));
}
__device__ __forceinline__ _Float16 lo_half(const _Float16* p) {
  unsigned v = *(const unsigned*)p;
  return __builtin_bit_cast(_Float16, (unsigned short)v);
}
__device__ __forceinline__ _Float16 hmax(_Float16 a, _Float16 b) {
  return a > b ? a : b;
}

// Erode 3x1/1x3-min stencil for a row pair at (r0, group gg): outputs oA
// (row r0) and oB (row r0+1). Reads rows r0-1..r0+2. m=min(b,c) shared.
#define ERODE_AT(r0, gg, oA, oB)                                          \
  {                                                                       \
    const _Float16* s0 = buf + ((r0)-1) * SW + 8 * (GLO + (gg));          \
    h8 a = *(const h8*)(s0);                                              \
    h8 b = *(const h8*)(s0 + SW);                                         \
    h8 c = *(const h8*)(s0 + 2 * SW);                                     \
    h8 d = *(const h8*)(s0 + 3 * SW);                                     \
    _Float16 le0 = hi_half(s0 + SW - 2);                                  \
    _Float16 le1 = hi_half(s0 + 2 * SW - 2);                              \
    _Float16 re0 = lo_half(s0 + SW + 8);                                  \
    _Float16 re1 = lo_half(s0 + 2 * SW + 8);                              \
    h8 m = __builtin_elementwise_min(b, c);                               \
    oA = __builtin_elementwise_min(                                       \
        __builtin_elementwise_min(__builtin_elementwise_min(a, m),        \
                                  shl1(b, le0)),                          \
        shr1(b, re0));                                                    \
    oB = __builtin_elementwise_min(                                       \
        __builtin_elementwise_min(__builtin_elementwise_min(m, d),        \
                                  shl1(c, le1)),                          \
        shr1(c, re1));                                                    \
  }

#define WRITE_AT(r0, gg, oA, oB)                             \
  {                                                          \
    _Float16* d0 = buf + (r0)*SW + 8 * (GLO + (gg));         \
    *(h8*)(d0) = oA;                                         \
    *(h8*)(d0 + SW) = oB;                                    \
  }

// One full in-place erode pass (compute -> barrier -> write -> barrier).
// All state in named registers spanning the barriers (R2 scratch lesson).
template <int G, int GLO>
__device__ __forceinline__ void erode_pass(_Float16* buf, int tid, int rb,
                                           int items) {
  const int rp0 = tid / G;  // G compile-time: magic-multiply
  const int g0 = tid - rp0 * G;
  const int r00 = rb + 2 * rp0;

  const int it1 = tid + NT;
  const int rp1 = it1 / G;
  const int g1 = it1 - rp1 * G;
  const int r01 = rb + 2 * rp1;

  const int it2 = tid + 2 * NT;
  const bool a2 = it2 < items;
  const int rp2 = it2 / G;
  const int g2 = it2 - rp2 * G;
  const int r02 = rb + 2 * rp2;

  h8 o00, o01, o10, o11, o20, o21;
  ERODE_AT(r00, g0, o00, o01);   // k=0 unconditional (items>=1170)
  ERODE_AT(r01, g1, o10, o11);   // k=1 unconditional (items>=1170>=1024)
  if (a2) ERODE_AT(r02, g2, o20, o21);

  __syncthreads();  // A: all reads of the old level complete

  WRITE_AT(r00, g0, o00, o01);
  WRITE_AT(r01, g1, o10, o11);
  if (a2) WRITE_AT(r02, g2, o20, o21);

  __syncthreads();  // B: new level fully in buf
}

__global__ __launch_bounds__(NT, 4) void cl_skel_kernel(
    const float* __restrict__ pred, const float* __restrict__ target,
    double* __restrict__ sums) {
  __shared__ _Float16 buf[SROWS * SW];
  __shared__ float rbuf[2][NT / 64];

  const int tid = threadIdx.x;
  const int tileIdx = blockIdx.x;        // 0..15: 4 row-tiles x 4 col-tiles
  const int batch = blockIdx.y;
  const bool isPred = (blockIdx.z == 0);
  const int tr = (tileIdx >> 2) * TH;
  const int tc = (tileIdx & 3) * TW;
  const float* __restrict__ img = isPred ? pred : target;
  const float* __restrict__ other = isPred ? target : pred;
  const size_t base = (size_t)batch * (H * W);

  const bool border = (tr == 0) | (tc == 0) | (tr == H - TH) | (tc == W - TW);

  // ---- Stage x0 (fp16): LDS rows 1..152, half cols 0..159 (40 groups) ----
  if (!border) {
    for (int it = tid; it < 152 * 40; it += NT) {
      int row = 1 + it / 40, g = it - (row - 1) * 40;
      int gr = tr - 13 + row;
      int gc = tc - 16 + 4 * g;
      float4 v = ld4(&img[base + (size_t)gr * W + gc]);
      if (isPred) {
        v.x = sigmf(v.x); v.y = sigmf(v.y); v.z = sigmf(v.z); v.w = sigmf(v.w);
      }
      h4 hv;
      hv[0] = (_Float16)v.x; hv[1] = (_Float16)v.y;
      hv[2] = (_Float16)v.z; hv[3] = (_Float16)v.w;
      *(h4*)(buf + row * SW + 4 * g) = hv;
    }
  } else {
    for (int it = tid; it < 152 * 40; it += NT) {
      int row = 1 + it / 40, g = it - (row - 1) * 40;
      int gr = min(max(tr - 13 + row, 0), H - 1);
      int gc = tc - 16 + 4 * g;
      float4 v;
      v.x = img[base + (size_t)gr * W + min(max(gc + 0, 0), W - 1)];
      v.y = img[base + (size_t)gr * W + min(max(gc + 1, 0), W - 1)];
      v.z = img[base + (size_t)gr * W + min(max(gc + 2, 0), W - 1)];
      v.w = img[base + (size_t)gr * W + min(max(gc + 3, 0), W - 1)];
      if (isPred) {
        v.x = sigmf(v.x); v.y = sigmf(v.y); v.z = sigmf(v.z); v.w = sigmf(v.w);
      }
      h4 hv;
      hv[0] = (_Float16)v.x; hv[1] = (_Float16)v.y;
      hv[2] = (_Float16)v.z; hv[3] = (_Float16)v.w;
      *(h4*)(buf + row * SW + 4 * g) = hv;
    }
  }
  __syncthreads();

  const int ty = tid >> 3;  // 0..63: own row-pair index
  const int tg = tid & 7;   // 0..7 : own 16-col group
  const int rr0 = 13 + 2 * ty;   // own rows rr0, rr0+1
  const int c0 = 16 + 16 * tg;

  h8 skelE0 = (h8)(_Float16)0.0f, skelF0 = (h8)(_Float16)0.0f;
  h8 skelE1 = (h8)(_Float16)0.0f, skelF1 = (h8)(_Float16)0.0f;

#pragma unroll 1
  for (int R = 11; R >= 1; --R) {
    const int rb = 13 - R;

    // t0 = x_{k-1} at own 32 px — read before any in-place write (pre-A)
    const _Float16* ps = buf + rr0 * SW + c0;
    h8 t0E0 = *(const h8*)ps,        t0F0 = *(const h8*)(ps + 8);
    h8 t0E1 = *(const h8*)(ps + SW), t0F1 = *(const h8*)(ps + SW + 8);

    if (R >= 9) {
      erode_pass<20, 0>(buf, tid, rb, (64 + R) * 20);
    } else {
      erode_pass<18, 1>(buf, tid, rb, (64 + R) * 18);
    }

    // ---- dilate(buf) at own 2 rows x 16 px; skel update ----
    {
      const _Float16* pm = buf + (rr0 - 1) * SW + c0;
      h8 aE = *(const h8*)(pm),          aF = *(const h8*)(pm + 8);
      h8 bE = *(const h8*)(pm + SW),     bF = *(const h8*)(pm + SW + 8);
      h8 cE = *(const h8*)(pm + 2 * SW), cF = *(const h8*)(pm + 2 * SW + 8);
      h8 dE = *(const h8*)(pm + 3 * SW), dF = *(const h8*)(pm + 3 * SW + 8);
      _Float16 e0 = hi_half(pm - 2);
      _Float16 e1 = hi_half(pm + SW - 2);
      _Float16 e2 = hi_half(pm + 2 * SW - 2);
      _Float16 e3 = hi_half(pm + 3 * SW - 2);
      _Float16 w0 = lo_half(pm + 16);
      _Float16 w1 = lo_half(pm + SW + 16);
      _Float16 w2 = lo_half(pm + 2 * SW + 16);
      _Float16 w3 = lo_half(pm + 3 * SW + 16);
      _Float16 eml = hmax(e1, e2), wml = hmax(w1, w2);
      _Float16 vl0 = hmax(e0, eml), vl1 = hmax(eml, e3);
      _Float16 vr0 = hmax(w0, wml), vr1 = hmax(wml, w3);
      h8 mE = __builtin_elementwise_max(bE, cE);
      h8 mF = __builtin_elementwise_max(bF, cF);
      h8 vm0E = __builtin_elementwise_max(aE, mE);
      h8 vm0F = __builtin_elementwise_max(aF, mF);
      h8 vm1E = __builtin_elementwise_max(mE, dE);
      h8 vm1F = __builtin_elementwise_max(mF, dF);
      h8 z = (h8)(_Float16)0.0f;
      {
        h8 hE = max3v(shl1(vm0E, vl0), vm0E, shr1(vm0E, vm0F[0]));
        h8 hF = max3v(shl1(vm0F, vm0E[7]), vm0F, shr1(vm0F, vr0));
        h8 dE_ = __builtin_elementwise_max(t0E0 - hE, z);
        h8 dF_ = __builtin_elementwise_max(t0F0 - hF, z);
        skelE0 += __builtin_elementwise_max(dE_ - skelE0 * dE_, z);
        skelF0 += __builtin_elementwise_max(dF_ - skelF0 * dF_, z);
      }
      {
        h8 hE = max3v(shl1(vm1E, vl1), vm1E, shr1(vm1E, vm1F[0]));
        h8 hF = max3v(shl1(vm1F, vm1E[7]), vm1F, shr1(vm1F, vr1));
        h8 dE_ = __builtin_elementwise_max(t0E1 - hE, z);
        h8 dF_ = __builtin_elementwise_max(t0F1 - hF, z);
        skelE1 += __builtin_elementwise_max(dE_ - skelE1 * dE_, z);
        skelF1 += __builtin_elementwise_max(dF_ - skelF1 * dF_, z);
      }
    }
    // next pass reads buf (level R) pre-its-barrier-A: reads only, safe.
  }

  // ---- Products with the other image over own 2x16 px (epilogue loads) ----
  float s0 = 0.0f, s1 = 0.0f;
  {
    const float* orow = other + base + (size_t)(tr + 2 * ty) * W + tc + 16 * tg;
#pragma unroll
    for (int q = 0; q < 4; ++q) {
      float4 o = ld4(orow + 4 * q);
      if (!isPred) {
        o.x = sigmf(o.x); o.y = sigmf(o.y); o.z = sigmf(o.z); o.w = sigmf(o.w);
      }
      float sk0, sk1, sk2, sk3;
      if (q < 2) {
        sk0 = (float)skelE0[4 * q + 0]; sk1 = (float)skelE0[4 * q + 1];
        sk2 = (float)skelE0[4 * q + 2]; sk3 = (float)skelE0[4 * q + 3];
      } else {
        sk0 = (float)skelF0[4 * q - 8]; sk1 = (float)skelF0[4 * q - 7];
        sk2 = (float)skelF0[4 * q - 6]; sk3 = (float)skelF0[4 * q - 5];
      }
      s0 += (sk0 + sk1) + (sk2 + sk3);
      s1 += (sk0 * o.x + sk1 * o.y) + (sk2 * o.z + sk3 * o.w);
    }
    const float* orow1 = orow + W;
#pragma unroll
    for (int q = 0; q < 4; ++q) {
      float4 o = ld4(orow1 + 4 * q);
      if (!isPred) {
        o.x = sigmf(o.x); o.y = sigmf(o.y); o.z = sigmf(o.z); o.w = sigmf(o.w);
      }
      float sk0, sk1, sk2, sk3;
      if (q < 2) {
        sk0 = (float)skelE1[4 * q + 0]; sk1 = (float)skelE1[4 * q + 1];
        sk2 = (float)skelE1[4 * q + 2]; sk3 = (float)skelE1[4 * q + 3];
      } else {
        sk0 = (float)skelF1[4 * q - 8]; sk1 = (float)skelF1[4 * q - 7];
        sk2 = (float)skelF1[4 * q - 6]; sk3 = (float)skelF1[4 * q - 5];
      }
      s0 += (sk0 + sk1) + (sk2 + sk3);
      s1 += (sk0 * o.x + sk1 * o.y) + (sk2 * o.z + sk3 * o.w);
    }
  }

#pragma unroll
  for (int off = 32; off > 0; off >>= 1) {
    s0 += __shfl_down(s0, off, 64);
    s1 += __shfl_down(s1, off, 64);
  }
  const int wave = tid >> 6;
  const int lane = tid & 63;
  if (lane == 0) {
    rbuf[0][wave] = s0;
    rbuf[1][wave] = s1;
  }
  __syncthreads();
  if (tid == 0) {
    float t0 = 0.0f, t1 = 0.0f;
#pragma unroll
    for (int w = 0; w < NT / 64; ++w) {
      t0 += rbuf[0][w];
      t1 += rbuf[1][w];
    }
    const int bank = (int)(blockIdx.x & (NBANKS - 1));
    const int o2 = (isPred ? 0 : 2);
    atomicAdd(&sums[bank * BANK_STRIDE + o2], (double)t0);
    atomicAdd(&sums[bank * BANK_STRIDE + o2 + 1], (double)t1);
  }
}

__global__ void cl_finalize_kernel(const double* __restrict__ sums,
                                   float* __restrict__ out) {
  double s[4] = {0.0, 0.0, 0.0, 0.0};
  for (int b = 0; b < NBANKS; ++b)
    for (int j = 0; j < 4; ++j) s[j] += sums[b * BANK_STRIDE + j];
  double tprec = (s[1] + 1.0) / (s[0] + 1.0);
  double tsens = (s[3] + 1.0) / (s[2] + 1.0);
  double cl = 2.0 * tprec * tsens / (tprec + tsens + 1e-7);
  out[0] = (float)(1.0 - cl);
}

extern "C" void kernel_launch(void* const* d_in, const int* in_sizes, int n_in,
                              void* d_out, int out_size, void* d_ws,
                              size_t ws_size, hipStream_t stream) {
  const float* pred = (const float*)d_in[0];
  const float* target = (const float*)d_in[1];
  double* sums = (double*)d_ws;
  const int batch = in_sizes[0] / (H * W);  // 32

  hipMemsetAsync(d_ws, 0, NBANKS * BANK_STRIDE * sizeof(double), stream);
  dim3 grid((H / TH) * (W / TW), batch, 2);
  cl_skel_kernel<<<grid, NT, 0, stream>>>(pred, target, sums);
  cl_finalize_kernel<<<1, 1, 0, stream>>>(sums, (float*)d_out);
}

// Round 19
// 196.855 us; speedup vs baseline: 1.0416x; 1.0416x over previous
//
#include <hip/hip_runtime.h>

#define H 512
#define W 512
#define TH 64                 // tile rows
#define TW 128                // tile cols
#define NT 512
#define SW 168                // LDS row stride in halfs (84 dwords; 8 staged-pad)
#define SROWS 90
#define NBANKS 16
#define BANK_STRIDE 16
// 64x128 tile, px (y,x) at LDS (13+y, 16+x) fp16, staged cols 0..159
// (pad 160..167 uninit -- feeds only never-consumed edge cols, see proof).
//
// MEASURED LADDER (steady-state dispatch): 64x64 in-place (R7) 137us ->
// +diet (R15) 135us -> 64x128 (R16) 125us CHAMPION -> 128x128 (R17) 132us
// REGRESSION (occ 57->39 from 52KB LDS, conflicts 2.1e7->3.3e7). This file
// is the R16 champion, verbatim. Geometry U-shape bracketed: 64x128 is
// the optimum. Remaining ~30% non-VALU time is barrier drain + LDS
// dependency latency across 22 dependent block-wide passes -- structural
// (R10/R11: structure changes cost more in instructions/occupancy than
// they recover).
//
// Diet (R15, banked): rcp-sigmoid (~9 VALU -> 1, err 1e-7 << fp16
// quantum), min(b,c) CSE in erode, stage rows 1..89 only.
//
// In-place safety: pass R writes rows [13-R,76+R], reads [12-R,77+R] ==
// prev pass's written rows (margin 0); all reads (incl. t0) pre-barrier-A,
// writes A->B, dilate after B reads the new level only. Stage rows 1..89
// (R=11 reads rows [1,88]).
// COLUMN TRIM/validity: pass R consumed cols [16-R,143+R]. G=20/GLO=0
// (R>=9, writes cols [0,159]), G=18/GLO=1 (R<=8, writes [8,151]).
// V(11)=[1,158], V(10)=[2,157], V(9)=[3,156], V(8)=[8,151], V(7)=[9,150],
// ..., V(1)=[15,144] exact = final dilate cols; margin >=0 at every pass
// (stale/garbage cols advance 1/pass, always outside consumed range).
// items: min 594 (R=1) >= NT -> k=0 unconditional; max 860 < 2*NT -> k=1
// guarded only.

typedef _Float16 h8 __attribute__((ext_vector_type(8)));
typedef _Float16 h4 __attribute__((ext_vector_type(4)));

__device__ __forceinline__ float sigmf(float x) {
  // 1/(1+e^-x) with hw rcp: full IEEE divide is ~9 VALU ops, rcp is 1.
  return __builtin_amdgcn_rcpf(1.0f + __expf(-x));
}
__device__ __forceinline__ float4 ld4(const float* p) { return *(const float4*)p; }

__device__ __forceinline__ h8 max3v(h8 a, h8 b, h8 c) {
  return __builtin_elementwise_max(__builtin_elementwise_max(a, b), c);
}
__device__ __forceinline__ h8 shl1(h8 v, _Float16 e) {
  h8 r = __builtin_shufflevector(v, v, 7, 0, 1, 2, 3, 4, 5, 6);
  r[0] = e;
  return r;
}
__device__ __forceinline__ h8 shr1(h8 v, _Float16 e) {
  h8 r = __builtin_shufflevector(v, v, 1, 2, 3, 4, 5, 6, 7, 0);
  r[7] = e;
  return r;
}
// b32 loads of half pairs (keeps ds_read2 mergeability), extract one half.
__device__ __forceinline__ _Float16 hi_half(const _Float16* p) {
  unsigned v = *(const unsigned*)p;
  return __builtin_bit_cast(_Float16, (unsigned short)(v >> 16));
}
__device__ __forceinline__ _Float16 lo_half(const _Float16* p) {
  unsigned v = *(const unsigned*)p;
  return __builtin_bit_cast(_Float16, (unsigned short)v);
}
__device__ __forceinline__ _Float16 hmax3(_Float16 a, _Float16 b, _Float16 c) {
  _Float16 m = a > b ? a : b;
  return m > c ? m : c;
}

// Erode 3x1/1x3-min stencil for a row pair at (r0, group gg): outputs oA
// (row r0) and oB (row r0+1). Reads rows r0-1..r0+2. m=min(b,c) shared.
#define ERODE_AT(r0, gg, oA, oB)                                          \
  {                                                                       \
    const _Float16* s0 = buf + ((r0)-1) * SW + 8 * (GLO + (gg));          \
    h8 a = *(const h8*)(s0);                                              \
    h8 b = *(const h8*)(s0 + SW);                                         \
    h8 c = *(const h8*)(s0 + 2 * SW);                                     \
    h8 d = *(const h8*)(s0 + 3 * SW);                                     \
    _Float16 le0 = hi_half(s0 + SW - 2);                                  \
    _Float16 le1 = hi_half(s0 + 2 * SW - 2);                              \
    _Float16 re0 = lo_half(s0 + SW + 8);                                  \
    _Float16 re1 = lo_half(s0 + 2 * SW + 8);                              \
    h8 m = __builtin_elementwise_min(b, c);                               \
    oA = __builtin_elementwise_min(                                       \
        __builtin_elementwise_min(__builtin_elementwise_min(a, m),        \
                                  shl1(b, le0)),                          \
        shr1(b, re0));                                                    \
    oB = __builtin_elementwise_min(                                       \
        __builtin_elementwise_min(__builtin_elementwise_min(m, d),        \
                                  shl1(c, le1)),                          \
        shr1(c, re1));                                                    \
  }

#define WRITE_AT(r0, gg, oA, oB)                             \
  {                                                          \
    _Float16* d0 = buf + (r0)*SW + 8 * (GLO + (gg));         \
    *(h8*)(d0) = oA;                                         \
    *(h8*)(d0 + SW) = oB;                                    \
  }

// One full in-place erode pass (compute -> barrier -> write -> barrier).
// All state in named registers spanning the barriers (R2 scratch lesson).
template <int G, int GLO>
__device__ __forceinline__ void erode_pass(_Float16* buf, int tid, int rb,
                                           int items) {
  const int rp0 = tid / G;  // G compile-time: magic-multiply
  const int g0 = tid - rp0 * G;
  const int r00 = rb + 2 * rp0;

  const int it1 = tid + NT;
  const bool a1 = it1 < items;
  const int rp1 = it1 / G;
  const int g1 = it1 - rp1 * G;
  const int r01 = rb + 2 * rp1;

  h8 o00, o01, o10, o11;
  ERODE_AT(r00, g0, o00, o01);            // k=0 always active (items>=594)
  if (a1) ERODE_AT(r01, g1, o10, o11);

  __syncthreads();  // A: all reads of the old level complete

  WRITE_AT(r00, g0, o00, o01);
  if (a1) WRITE_AT(r01, g1, o10, o11);

  __syncthreads();  // B: new level fully in buf
}

__global__ __launch_bounds__(NT, 4) void cl_skel_kernel(
    const float* __restrict__ pred, const float* __restrict__ target,
    double* __restrict__ sums) {
  __shared__ _Float16 buf[SROWS * SW];
  __shared__ float rbuf[2][NT / 64];

  const int tid = threadIdx.x;
  const int tileIdx = blockIdx.x;        // 0..31: 8 row-tiles x 4 col-tiles
  const int batch = blockIdx.y;
  const bool isPred = (blockIdx.z == 0);
  const int tr = (tileIdx >> 2) * TH;
  const int tc = (tileIdx & 3) * TW;
  const float* __restrict__ img = isPred ? pred : target;
  const float* __restrict__ other = isPred ? target : pred;
  const size_t base = (size_t)batch * (H * W);

  const bool border = (tr == 0) | (tc == 0) | (tr == H - TH) | (tc == W - TW);

  // ---- Stage x0 (fp16): LDS rows 1..89, half cols 0..159 (40 f4 groups) ----
  if (!border) {
    for (int it = tid; it < 89 * 40; it += NT) {
      int row = 1 + it / 40, g = it - (row - 1) * 40;
      int gr = tr - 13 + row;
      int gc = tc - 16 + 4 * g;
      float4 v = ld4(&img[base + (size_t)gr * W + gc]);
      if (isPred) {
        v.x = sigmf(v.x); v.y = sigmf(v.y); v.z = sigmf(v.z); v.w = sigmf(v.w);
      }
      h4 hv;
      hv[0] = (_Float16)v.x; hv[1] = (_Float16)v.y;
      hv[2] = (_Float16)v.z; hv[3] = (_Float16)v.w;
      *(h4*)(buf + row * SW + 4 * g) = hv;
    }
  } else {
    for (int it = tid; it < 89 * 40; it += NT) {
      int row = 1 + it / 40, g = it - (row - 1) * 40;
      int gr = min(max(tr - 13 + row, 0), H - 1);
      int gc = tc - 16 + 4 * g;
      float4 v;
      v.x = img[base + (size_t)gr * W + min(max(gc + 0, 0), W - 1)];
      v.y = img[base + (size_t)gr * W + min(max(gc + 1, 0), W - 1)];
      v.z = img[base + (size_t)gr * W + min(max(gc + 2, 0), W - 1)];
      v.w = img[base + (size_t)gr * W + min(max(gc + 3, 0), W - 1)];
      if (isPred) {
        v.x = sigmf(v.x); v.y = sigmf(v.y); v.z = sigmf(v.z); v.w = sigmf(v.w);
      }
      h4 hv;
      hv[0] = (_Float16)v.x; hv[1] = (_Float16)v.y;
      hv[2] = (_Float16)v.z; hv[3] = (_Float16)v.w;
      *(h4*)(buf + row * SW + 4 * g) = hv;
    }
  }
  __syncthreads();

  const int ty = tid >> 3;  // 0..63: own tile row
  const int tg = tid & 7;   // 0..7 : own 16-col group
  const int rr = 13 + ty;
  const int c0 = 16 + 16 * tg;

  h8 skelE = (h8)(_Float16)0.0f;
  h8 skelF = (h8)(_Float16)0.0f;

#pragma unroll 1
  for (int R = 11; R >= 1; --R) {
    const int rb = 13 - R;

    // t0 = x_{k-1} at own 16 px — read before any in-place write (pre-barrier A)
    const _Float16* ps = buf + rr * SW + c0;
    h8 t0E = *(const h8*)ps;
    h8 t0F = *(const h8*)(ps + 8);

    if (R >= 9) {
      erode_pass<20, 0>(buf, tid, rb, (32 + R) * 20);
    } else {
      erode_pass<18, 1>(buf, tid, rb, (32 + R) * 18);
    }

    // ---- dilate(buf) at own 16 px; skel update ----
    {
      const _Float16* pm = buf + (rr - 1) * SW + c0;
      h8 aE = *(const h8*)(pm),          aF = *(const h8*)(pm + 8);
      h8 bE = *(const h8*)(pm + SW),     bF = *(const h8*)(pm + SW + 8);
      h8 cE = *(const h8*)(pm + 2 * SW), cF = *(const h8*)(pm + 2 * SW + 8);
      _Float16 vl = hmax3(hi_half(pm - 2), hi_half(pm + SW - 2),
                          hi_half(pm + 2 * SW - 2));
      _Float16 vr = hmax3(lo_half(pm + 16), lo_half(pm + SW + 16),
                          lo_half(pm + 2 * SW + 16));
      h8 vmE = max3v(aE, bE, cE);
      h8 vmF = max3v(aF, bF, cF);
      h8 hE = max3v(shl1(vmE, vl), vmE, shr1(vmE, vmF[0]));
      h8 hF = max3v(shl1(vmF, vmE[7]), vmF, shr1(vmF, vr));
      h8 z = (h8)(_Float16)0.0f;
      h8 dE = __builtin_elementwise_max(t0E - hE, z);
      h8 dF = __builtin_elementwise_max(t0F - hF, z);
      skelE += __builtin_elementwise_max(dE - skelE * dE, z);
      skelF += __builtin_elementwise_max(dF - skelF * dF, z);
    }
    // next pass reads buf (level R) pre-its-barrier-A: reads only, safe.
  }

  // ---- Products with the other image over own 16 px (epilogue loads) ----
  const float* orow = other + base + (size_t)(tr + ty) * W + tc + 16 * tg;
  float s0 = 0.0f, s1 = 0.0f;
#pragma unroll
  for (int q = 0; q < 4; ++q) {
    float4 o = ld4(orow + 4 * q);
    if (!isPred) {
      o.x = sigmf(o.x); o.y = sigmf(o.y); o.z = sigmf(o.z); o.w = sigmf(o.w);
    }
    float sk0, sk1, sk2, sk3;
    if (q < 2) {
      sk0 = (float)skelE[4 * q + 0]; sk1 = (float)skelE[4 * q + 1];
      sk2 = (float)skelE[4 * q + 2]; sk3 = (float)skelE[4 * q + 3];
    } else {
      sk0 = (float)skelF[4 * q - 8]; sk1 = (float)skelF[4 * q - 7];
      sk2 = (float)skelF[4 * q - 6]; sk3 = (float)skelF[4 * q - 5];
    }
    s0 += (sk0 + sk1) + (sk2 + sk3);
    s1 += (sk0 * o.x + sk1 * o.y) + (sk2 * o.z + sk3 * o.w);
  }

#pragma unroll
  for (int off = 32; off > 0; off >>= 1) {
    s0 += __shfl_down(s0, off, 64);
    s1 += __shfl_down(s1, off, 64);
  }
  const int wave = tid >> 6;
  const int lane = tid & 63;
  if (lane == 0) {
    rbuf[0][wave] = s0;
    rbuf[1][wave] = s1;
  }
  __syncthreads();
  if (tid == 0) {
    float t0 = 0.0f, t1 = 0.0f;
#pragma unroll
    for (int w = 0; w < NT / 64; ++w) {
      t0 += rbuf[0][w];
      t1 += rbuf[1][w];
    }
    const int bank = (int)(blockIdx.x & (NBANKS - 1));
    const int o2 = (isPred ? 0 : 2);
    atomicAdd(&sums[bank * BANK_STRIDE + o2], (double)t0);
    atomicAdd(&sums[bank * BANK_STRIDE + o2 + 1], (double)t1);
  }
}

__global__ void cl_finalize_kernel(const double* __restrict__ sums,
                                   float* __restrict__ out) {
  double s[4] = {0.0, 0.0, 0.0, 0.0};
  for (int b = 0; b < NBANKS; ++b)
    for (int j = 0; j < 4; ++j) s[j] += sums[b * BANK_STRIDE + j];
  double tprec = (s[1] + 1.0) / (s[0] + 1.0);
  double tsens = (s[3] + 1.0) / (s[2] + 1.0);
  double cl = 2.0 * tprec * tsens / (tprec + tsens + 1e-7);
  out[0] = (float)(1.0 - cl);
}

extern "C" void kernel_launch(void* const* d_in, const int* in_sizes, int n_in,
                              void* d_out, int out_size, void* d_ws,
                              size_t ws_size, hipStream_t stream) {
  const float* pred = (const float*)d_in[0];
  const float* target = (const float*)d_in[1];
  double* sums = (double*)d_ws;
  const int batch = in_sizes[0] / (H * W);  // 32

  hipMemsetAsync(d_ws, 0, NBANKS * BANK_STRIDE * sizeof(double), stream);
  dim3 grid((H / TH) * (W / TW), batch, 2);
  cl_skel_kernel<<<grid, NT, 0, stream>>>(pred, target, sums);
  cl_finalize_kernel<<<1, 1, 0, stream>>>(sums, (float*)d_out);
}